// Round 11
// baseline (66.163 us; speedup 1.0000x reference)
//
#include <hip/hip_runtime.h>

typedef __bf16 bf16_t;
typedef __bf16 bf16x4 __attribute__((ext_vector_type(4)));
typedef __bf16 bf16x8 __attribute__((ext_vector_type(8)));
typedef float  f32x4  __attribute__((ext_vector_type(4)));

#define B_SZ  16
#define L_SEQ 2048
#define D_H   64
#define QB    128
#define KB    128

// softmax is over (S/8); fold log2(e)/8 into Q so MFMA output is in log2 units
#define QSCALE 0.18033688011112043f

// ws layout: Opart[256 slots][128*64] f32 (8 MB) | MLb[256][256] f32 (m:0..127, l:128..255) | Cnt[128] u32
#define OPART_FL  ((size_t)256 * QB * D_H)      // 2,097,152 floats
#define ML_FL     ((size_t)256 * 256)           // 65,536 floats

// ---------------- single fused kernel: 8-wave QB=128 engine, pair K-split, in-kernel merge ----
// pair p (0..7): tileL = 15-p (nktL = 16-p in 9..16), tileS = p (nktS = p+1 in 1..8)
// role 0 (front): tileL k-chunks 0..8                      (9 iters) -> partial
// role 1 (back):  tileL chunks 9..nktL-1 + all of tileS    (8 iters) -> partial + direct
// Whoever commits its tileL partial SECOND (arrival ticket) merges and writes O for tileL.
__global__ __launch_bounds__(512)
void attn_split_kernel(const float* __restrict__ Qg, const float* __restrict__ Kg,
                       const float* __restrict__ Vg, float* __restrict__ Og,
                       float* __restrict__ Opart, float* __restrict__ MLb,
                       unsigned* __restrict__ Cnt)
{
    const int lin  = blockIdx.x;          // 0..255
    const int xcd  = lin & 7;
    const int b    = xcd * 2 + ((lin >> 3) & 1);   // both roles of a pair on the same XCD
    const int p    = (lin >> 4) & 7;
    const int role = lin >> 7;
    const int pair = b * 8 + p;

    const int nktL = 16 - p;
    const int nktS = p + 1;
    const int cnt1 = role ? (nktL - 9) : 9;   // tileL iters this block
    const int cnt2 = role ? nktS : 0;
    const int total = cnt1 + cnt2;            // 9 (front) / 8 (back)

    const int tid  = threadIdx.x;
    const int wave = tid >> 6;             // 0..7
    const int lane = tid & 63;
    const int lg   = lane >> 4;
    const int lc   = lane & 15;
    const int lc7  = lc & 7;

    __shared__ __align__(16) bf16_t K_lds[2][KB * D_H];    // 32 KB  (XOR-swizzled)
    __shared__ __align__(16) bf16_t Vt_lds[2][D_H * KB];   // 32 KB  (transposed+phi+swizzled)
    __shared__ int sh_ticket;

    const size_t bbase = (size_t)b * L_SEQ * D_H;

    // ---- staging maps (512 threads): K 2 bf16x8-chunks/thread, V one 4x4 block/thread ----
    const int vkb  = tid & 31;            // k-block (4 rows) 0..31
    const int vdg  = tid >> 5;            // d-block 0..15
    const int vpos = ((vkb >> 3) << 5) + ((vkb & 3) << 3) + (((vkb >> 2) & 1) << 2);

    f32x4 kreg[4], vreg[4];

    auto issueK = [&](int kt) {
        const int kb = kt * KB;
#pragma unroll
        for (int i = 0; i < 2; ++i) {
            const int u = i * 512 + tid;
            const int r = u >> 3, ch = u & 7;
            const float* ptr = Kg + bbase + (size_t)(kb + r) * D_H + ch * 8;
            kreg[2 * i]     = *reinterpret_cast<const f32x4*>(ptr);
            kreg[2 * i + 1] = *reinterpret_cast<const f32x4*>(ptr + 4);
        }
    };
    auto issueV = [&](int kt) {
        const int kb = kt * KB;
#pragma unroll
        for (int i = 0; i < 4; ++i)
            vreg[i] = *reinterpret_cast<const f32x4*>(
                Vg + bbase + (size_t)(kb + vkb * 4 + i) * D_H + vdg * 4);
    };
    auto writeK = [&](int buf) {
#pragma unroll
        for (int i = 0; i < 2; ++i) {
            const int u = i * 512 + tid;
            const int r = u >> 3, ch = u & 7;
            bf16x8 kk;
#pragma unroll
            for (int j = 0; j < 4; ++j) { kk[j] = (bf16_t)kreg[2 * i][j]; kk[4 + j] = (bf16_t)kreg[2 * i + 1][j]; }
            *reinterpret_cast<bf16x8*>(&K_lds[buf][r * 64 + ((ch ^ (r & 7)) << 3)]) = kk;
        }
    };
    auto writeV = [&](int buf) {
        const int d0 = vdg * 4;
#pragma unroll
        for (int j = 0; j < 4; ++j) {
            const int d = d0 + j;
            bf16x4 cj = { (bf16_t)vreg[0][j], (bf16_t)vreg[1][j],
                          (bf16_t)vreg[2][j], (bf16_t)vreg[3][j] };
            const int hw = d * 128 + (((vpos >> 3) ^ (d & 7)) << 3) + (vpos & 7);
            *reinterpret_cast<bf16x4*>(&Vt_lds[buf][hw]) = cj;
        }
    };

    bf16x8 qa[2];
    auto loadQ = [&](int qt_) -> int {
        const int qr = qt_ * QB + wave * 16 + lc;
#pragma unroll
        for (int h = 0; h < 2; ++h) {
            const float* qp = Qg + bbase + (size_t)qr * D_H + h * 32 + lg * 8;
            const f32x4 f0 = *reinterpret_cast<const f32x4*>(qp);
            const f32x4 f1 = *reinterpret_cast<const f32x4*>(qp + 4);
            bf16x8 a;
#pragma unroll
            for (int j = 0; j < 4; ++j) { a[j] = (bf16_t)(f0[j] * QSCALE); a[4 + j] = (bf16_t)(f1[j] * QSCALE); }
            qa[h] = a;
        }
        return qr;
    };

    int qt = 15 - p, nktCur = nktL;
    int qrow = loadQ(qt);

    f32x4 o[4];
#pragma unroll
    for (int dt = 0; dt < 4; ++dt) o[dt] = (f32x4){0.f, 0.f, 0.f, 0.f};
    float m = -1e30f, l = 0.f;   // per-lane l partial in frame m

    auto writePartialL = [&]() {
        float lr = l;
        lr += __shfl_xor(lr, 16);
        lr += __shfl_xor(lr, 32);
        const int slot = pair * 2 + role;
        float* ob = Opart + (size_t)slot * (QB * D_H);
        const int qL = wave * 16 + lc;   // 0..127
#pragma unroll
        for (int dt = 0; dt < 4; ++dt)
            *reinterpret_cast<f32x4*>(&ob[qL * 64 + dt * 16 + lg * 4]) = o[dt];
        if (lg == 0) { MLb[slot * 256 + qL] = m; MLb[slot * 256 + 128 + qL] = lr; }
    };
    auto takeTicket = [&]() -> int {        // block-uniform call sites only
        __syncthreads();                    // all partial writes issued
        if (tid == 0) { __threadfence(); sh_ticket = (int)atomicAdd(&Cnt[pair], 1u); }
        __syncthreads();
        return sh_ticket;
    };
    auto doMergeL = [&]() {                 // second arriver combines both partials
        __threadfence();                    // acquire partner's partial
        const float* o0 = Opart + (size_t)(pair * 2) * (QB * D_H);
        const float* o1 = o0 + (QB * D_H);
        const int q  = tid >> 2;            // 0..127
        const int dc = (tid & 3) * 16;      // 0,16,32,48
        const float m0 = MLb[(pair * 2) * 256 + q],     l0 = MLb[(pair * 2) * 256 + 128 + q];
        const float m1 = MLb[(pair * 2 + 1) * 256 + q], l1 = MLb[(pair * 2 + 1) * 256 + 128 + q];
        const float mt = fmaxf(m0, m1);
        const float a0 = exp2f(m0 - mt), a1 = exp2f(m1 - mt);
        const float inv = 1.0f / (l0 * a0 + l1 * a1);
        const float* p0 = o0 + q * 64 + dc;
        const float* p1 = o1 + q * 64 + dc;
        float* og = Og + bbase + (size_t)((15 - p) * QB + q) * D_H + dc;
#pragma unroll
        for (int i = 0; i < 4; ++i) {
            const f32x4 v0 = *reinterpret_cast<const f32x4*>(p0 + i * 4);
            const f32x4 v1 = *reinterpret_cast<const f32x4*>(p1 + i * 4);
            f32x4 r;
#pragma unroll
            for (int k = 0; k < 4; ++k) r[k] = (v0[k] * a0 + v1[k] * a1) * inv;
            *reinterpret_cast<f32x4*>(og + i * 4) = r;
        }
    };

    auto seqKt = [&](int j) { return j < cnt1 ? 9 * role + j : j - cnt1; };

    bool mergeLater = false;

    // ---- prologue: stage first tile ----
    issueK(seqKt(0)); issueV(seqKt(0)); writeK(0); writeV(0);
    __syncthreads();
    int cur = 0;

    for (int j = 0; j < total; ++j) {
        if (role && j == cnt1) {
            // commit tileL partial (possibly empty), take ticket, switch to tileS
            writePartialL();
            mergeLater = (takeTicket() == 1);
            qt = p; nktCur = nktS; qrow = loadQ(qt);
#pragma unroll
            for (int dt = 0; dt < 4; ++dt) o[dt] = (f32x4){0.f, 0.f, 0.f, 0.f};
            m = -1e30f; l = 0.f;
        }
        const int kt   = seqKt(j);
        const int kb0  = kt * KB;
        const bool more = (j + 1 < total);
        if (more) issueK(seqKt(j + 1));

        // ---- S^T = K Q^T (log2 units): sc[n][r] = S[k=kb0+n*16+lg*4+r][q=qrow] ----
        f32x4 sc[8];
        __builtin_amdgcn_s_setprio(1);
#pragma unroll
        for (int n = 0; n < 8; ++n) {
            f32x4 acc = (f32x4){0.f, 0.f, 0.f, 0.f};
#pragma unroll
            for (int h = 0; h < 2; ++h) {
                const int hw = (n * 16 + lc) * 64 + ((((h << 2) | lg) ^ lc7) << 3);
                const bf16x8 kkb = *reinterpret_cast<const bf16x8*>(&K_lds[cur][hw]);
                acc = __builtin_amdgcn_mfma_f32_16x16x32_bf16(kkb, qa[h], acc, 0, 0, 0);
            }
            sc[n] = acc;
        }
        __builtin_amdgcn_s_setprio(0);
        if (more) issueV(seqKt(j + 1));
        if (kt == nktCur - 1) {   // diagonal chunk: causal mask
#pragma unroll
            for (int n = 0; n < 8; ++n)
#pragma unroll
                for (int r = 0; r < 4; ++r)
                    if (kb0 + n * 16 + lg * 4 + r > qrow) sc[n][r] = -1e30f;
        }

        // ---- defer-max online softmax (per-lane; cross-lane only on slow path) ----
        float mxp = fmaxf(fmaxf(sc[0][0], sc[0][1]), fmaxf(sc[0][2], sc[0][3]));
#pragma unroll
        for (int n = 1; n < 8; ++n)
            mxp = fmaxf(mxp, fmaxf(fmaxf(sc[n][0], sc[n][1]), fmaxf(sc[n][2], sc[n][3])));
        if (!__all(mxp <= m + 8.0f)) {
            float mx = mxp;
            mx = fmaxf(mx, __shfl_xor(mx, 16));
            mx = fmaxf(mx, __shfl_xor(mx, 32));
            const float mn = fmaxf(m, mx);
            const float alpha = exp2f(m - mn);
            m = mn;
            l *= alpha;
#pragma unroll
            for (int dt = 0; dt < 4; ++dt)
#pragma unroll
                for (int r = 0; r < 4; ++r) o[dt][r] *= alpha;
        }
        // P packed directly into the PV B-operand layout (phi-permuted V^T)
        bf16x8 w[4];
        float rs = 0.f;
#pragma unroll
        for (int n = 0; n < 8; ++n) {
            const float p0 = exp2f(sc[n][0] - m), p1 = exp2f(sc[n][1] - m);
            const float p2 = exp2f(sc[n][2] - m), p3 = exp2f(sc[n][3] - m);
            rs += (p0 + p1) + (p2 + p3);
            const int wi = n >> 1, off = (n & 1) * 4;
            w[wi][off + 0] = (bf16_t)p0; w[wi][off + 1] = (bf16_t)p1;
            w[wi][off + 2] = (bf16_t)p2; w[wi][off + 3] = (bf16_t)p3;
        }
        l += rs;

        if (more) writeK(cur ^ 1);   // free kreg before PV

        // ---- O^T += V^T P : P straight from registers, V^T from swizzled LDS ----
        __builtin_amdgcn_s_setprio(1);
#pragma unroll
        for (int ks = 0; ks < 4; ++ks) {
#pragma unroll
            for (int dt = 0; dt < 4; ++dt) {
                const int hw = (dt * 16 + lc) * 128 + ((((ks << 2) | lg) ^ lc7) << 3);
                const bf16x8 vb = *reinterpret_cast<const bf16x8*>(&Vt_lds[cur][hw]);
                o[dt] = __builtin_amdgcn_mfma_f32_16x16x32_bf16(vb, w[ks], o[dt], 0, 0, 0);
            }
        }
        __builtin_amdgcn_s_setprio(0);

        if (more) writeV(cur ^ 1);
        __syncthreads();
        cur ^= 1;
    }

    if (role == 0) {
        writePartialL();
        if (takeTicket() == 1) doMergeL();
    } else {
        // back: tileS complete -> divide and write directly
        float lr = l;
        lr += __shfl_xor(lr, 16);
        lr += __shfl_xor(lr, 32);
        const float inv = 1.0f / lr;
#pragma unroll
        for (int dt = 0; dt < 4; ++dt) {
            f32x4 val = { o[dt][0] * inv, o[dt][1] * inv, o[dt][2] * inv, o[dt][3] * inv };
            *reinterpret_cast<f32x4*>(Og + bbase + (size_t)qrow * D_H + dt * 16 + lg * 4) = val;
        }
        if (mergeLater) doMergeL();
    }
}

// ---------------- fallback (no-ws path, round-6 kernel) ----------------
__global__ __launch_bounds__(256, 2)
void attn_fwd_fb(const float* __restrict__ Qg, const float* __restrict__ Kg,
                 const float* __restrict__ Vg, float* __restrict__ Og)
{
    const int lin  = blockIdx.x;
    const int xcd  = lin & 7;
    const int slot = lin >> 3;
    const int half = slot >> 5;
    const int qi   = slot & 31;
    const int b    = xcd * 2 + half;
    const int qt   = half ? qi : (31 - qi);

    const int tid  = threadIdx.x;
    const int lane = tid & 63;
    const int lg   = lane >> 4;
    const int lc   = lane & 15;
    const int lc7  = lc & 7;

    __shared__ __align__(16) bf16_t K_lds[2][KB * D_H];
    __shared__ __align__(16) bf16_t Vt_lds[2][D_H * KB];

    const size_t bbase = (size_t)b * L_SEQ * D_H;
    const int qrow = qt * 64 + (tid >> 6) * 16 + lc;
    bf16x8 qa[2];
#pragma unroll
    for (int h = 0; h < 2; ++h) {
        const float* qp = Qg + bbase + (size_t)qrow * D_H + h * 32 + lg * 8;
        const f32x4 f0 = *reinterpret_cast<const f32x4*>(qp);
        const f32x4 f1 = *reinterpret_cast<const f32x4*>(qp + 4);
        bf16x8 a;
#pragma unroll
        for (int j = 0; j < 4; ++j) { a[j] = (bf16_t)(f0[j] * QSCALE); a[4 + j] = (bf16_t)(f1[j] * QSCALE); }
        qa[h] = a;
    }
    f32x4 o[4];
#pragma unroll
    for (int dt = 0; dt < 4; ++dt) o[dt] = (f32x4){0.f, 0.f, 0.f, 0.f};
    float m = -1e30f, l = 0.f;
    const int nkt = (qt + 2) >> 1;
    const int vkb  = tid & 31;
    const int vdg  = tid >> 5;
    const int vpos = ((vkb >> 3) << 5) + ((vkb & 3) << 3) + (((vkb >> 2) & 1) << 2);
    f32x4 kreg[8], vreg[8];

    auto issueK = [&](int kt) {
        const int kbase = kt * KB;
#pragma unroll
        for (int i = 0; i < 4; ++i) {
            const int u = i * 256 + tid;
            const int r = u >> 3, ch = u & 7;
            const float* p = Kg + bbase + (size_t)(kbase + r) * D_H + ch * 8;
            kreg[2 * i]     = *reinterpret_cast<const f32x4*>(p);
            kreg[2 * i + 1] = *reinterpret_cast<const f32x4*>(p + 4);
        }
    };
    auto issueV = [&](int kt) {
        const int kbase = kt * KB;
#pragma unroll
        for (int d2 = 0; d2 < 2; ++d2)
#pragma unroll
            for (int i = 0; i < 4; ++i)
                vreg[d2 * 4 + i] = *reinterpret_cast<const f32x4*>(
                    Vg + bbase + (size_t)(kbase + vkb * 4 + i) * D_H + (vdg + d2 * 8) * 4);
    };
    auto writeK = [&](int buf) {
#pragma unroll
        for (int i = 0; i < 4; ++i) {
            const int u = i * 256 + tid;
            const int r = u >> 3, ch = u & 7;
            bf16x8 kk;
#pragma unroll
            for (int j = 0; j < 4; ++j) { kk[j] = (bf16_t)kreg[2 * i][j]; kk[4 + j] = (bf16_t)kreg[2 * i + 1][j]; }
            *reinterpret_cast<bf16x8*>(&K_lds[buf][r * 64 + ((ch ^ (r & 7)) << 3)]) = kk;
        }
    };
    auto writeV = [&](int buf) {
#pragma unroll
        for (int d2 = 0; d2 < 2; ++d2) {
            const int db = vdg + d2 * 8;
#pragma unroll
            for (int j = 0; j < 4; ++j) {
                const int d = db * 4 + j;
                bf16x4 cj = { (bf16_t)vreg[d2 * 4 + 0][j], (bf16_t)vreg[d2 * 4 + 1][j],
                              (bf16_t)vreg[d2 * 4 + 2][j], (bf16_t)vreg[d2 * 4 + 3][j] };
                const int hw = d * 128 + (((vpos >> 3) ^ (d & 7)) << 3) + (vpos & 7);
                *reinterpret_cast<bf16x4*>(&Vt_lds[buf][hw]) = cj;
            }
        }
    };

    issueK(0); issueV(0); writeK(0); writeV(0);
    __syncthreads();
    int cur = 0;
    for (int kt = 0; kt < nkt; ++kt) {
        const bool last = (kt == nkt - 1);
        const int kbase = kt * KB;
        if (!last) issueK(kt + 1);
        f32x4 sc[8];
#pragma unroll
        for (int n = 0; n < 8; ++n) {
            f32x4 acc = (f32x4){0.f, 0.f, 0.f, 0.f};
#pragma unroll
            for (int h = 0; h < 2; ++h) {
                const int hw = (n * 16 + lc) * 64 + ((((h << 2) | lg) ^ lc7) << 3);
                const bf16x8 kkb = *reinterpret_cast<const bf16x8*>(&K_lds[cur][hw]);
                acc = __builtin_amdgcn_mfma_f32_16x16x32_bf16(kkb, qa[h], acc, 0, 0, 0);
            }
            sc[n] = acc;
        }
        if (!last) issueV(kt + 1);
        if (last) {
#pragma unroll
            for (int n = 0; n < 8; ++n)
#pragma unroll
                for (int r = 0; r < 4; ++r)
                    if (kbase + n * 16 + lg * 4 + r > qrow) sc[n][r] = -1e30f;
        }
        float mxp = fmaxf(fmaxf(sc[0][0], sc[0][1]), fmaxf(sc[0][2], sc[0][3]));
#pragma unroll
        for (int n = 1; n < 8; ++n)
            mxp = fmaxf(mxp, fmaxf(fmaxf(sc[n][0], sc[n][1]), fmaxf(sc[n][2], sc[n][3])));
        if (!__all(mxp <= m + 8.0f)) {
            float mx = mxp;
            mx = fmaxf(mx, __shfl_xor(mx, 16));
            mx = fmaxf(mx, __shfl_xor(mx, 32));
            const float mn = fmaxf(m, mx);
            const float alpha = exp2f(m - mn);
            m = mn; l *= alpha;
#pragma unroll
            for (int dt = 0; dt < 4; ++dt)
#pragma unroll
                for (int r = 0; r < 4; ++r) o[dt][r] *= alpha;
        }
        bf16x8 w[4];
        float rs = 0.f;
#pragma unroll
        for (int n = 0; n < 8; ++n) {
            const float p0 = exp2f(sc[n][0] - m), p1 = exp2f(sc[n][1] - m);
            const float p2 = exp2f(sc[n][2] - m), p3 = exp2f(sc[n][3] - m);
            rs += (p0 + p1) + (p2 + p3);
            const int wi = n >> 1, off = (n & 1) * 4;
            w[wi][off + 0] = (bf16_t)p0; w[wi][off + 1] = (bf16_t)p1;
            w[wi][off + 2] = (bf16_t)p2; w[wi][off + 3] = (bf16_t)p3;
        }
        l += rs;
        if (!last) writeK(cur ^ 1);
#pragma unroll
        for (int ks = 0; ks < 4; ++ks) {
#pragma unroll
            for (int dt = 0; dt < 4; ++dt) {
                const int hw = (dt * 16 + lc) * 128 + ((((ks << 2) | lg) ^ lc7) << 3);
                const bf16x8 vb = *reinterpret_cast<const bf16x8*>(&Vt_lds[cur][hw]);
                o[dt] = __builtin_amdgcn_mfma_f32_16x16x32_bf16(vb, w[ks], o[dt], 0, 0, 0);
            }
        }
        if (!last) writeV(cur ^ 1);
        __syncthreads();
        cur ^= 1;
    }
    float lr = l;
    lr += __shfl_xor(lr, 16);
    lr += __shfl_xor(lr, 32);
    const float inv = 1.0f / lr;
#pragma unroll
    for (int dt = 0; dt < 4; ++dt) {
        f32x4 val = { o[dt][0] * inv, o[dt][1] * inv, o[dt][2] * inv, o[dt][3] * inv };
        *reinterpret_cast<f32x4*>(Og + bbase + (size_t)qrow * D_H + dt * 16 + lg * 4) = val;
    }
}

extern "C" void kernel_launch(void* const* d_in, const int* in_sizes, int n_in,
                              void* d_out, int out_size, void* d_ws, size_t ws_size,
                              hipStream_t stream)
{
    const float* Q = (const float*)d_in[0];
    const float* K = (const float*)d_in[1];
    const float* V = (const float*)d_in[2];
    float* O = (float*)d_out;

    const size_t need = (OPART_FL + ML_FL) * sizeof(float) + 128 * sizeof(unsigned);  // ~8.9 MB
    if (ws_size >= need) {
        float*    Opart = (float*)d_ws;
        float*    MLb   = Opart + OPART_FL;
        unsigned* Cnt   = (unsigned*)(MLb + ML_FL);
        hipMemsetAsync(Cnt, 0, 128 * sizeof(unsigned), stream);
        attn_split_kernel<<<dim3(256), dim3(512), 0, stream>>>(Q, K, V, O, Opart, MLb, Cnt);
    } else {
        attn_fwd_fb<<<dim3(512), dim3(256), 0, stream>>>(Q, K, V, O);
    }
}

// Round 12
// 39.631 us; speedup vs baseline: 1.6695x; 1.6695x over previous
//
#include <hip/hip_runtime.h>

typedef __bf16 bf16_t;
typedef __bf16 bf16x4 __attribute__((ext_vector_type(4)));
typedef __bf16 bf16x8 __attribute__((ext_vector_type(8)));
typedef float  f32x4  __attribute__((ext_vector_type(4)));

#define B_SZ  16
#define L_SEQ 2048
#define D_H   64
#define QB    128
#define KB    128
#define NT128 16                 // L_SEQ / KB
#define TILE_HW (KB * D_H)       // 8192 bf16 per tile image (16 KB)
#define IMG_ELEMS ((size_t)B_SZ * NT128 * TILE_HW)   // per tensor

// softmax is over (S/8); fold log2(e)/8 into Q so MFMA output is in log2 units
#define QSCALE 0.18033688011112043f

#define GLD_LDS16(g, l) __builtin_amdgcn_global_load_lds(                       \
    (const __attribute__((address_space(1))) void*)(g),                         \
    (__attribute__((address_space(3))) void*)(l), 16, 0, 0)

// ---------------- preproc: bf16 + transpose(V) + XOR-swizzle baked into ws images ----
// 4x parallelism vs r10: grid (16,16,4); each thread does ONE K-chunk + ONE V-chunk.
__global__ __launch_bounds__(256)
void preproc_kernel(const float* __restrict__ Kg, const float* __restrict__ Vg,
                    bf16_t* __restrict__ Kimg, bf16_t* __restrict__ Vimg)
{
    const int kt = blockIdx.x, b = blockIdx.y, z = blockIdx.z;   // z = quarter
    const int t  = threadIdx.x;
    const size_t src = (size_t)b * L_SEQ * D_H + (size_t)kt * KB * D_H;
    bf16_t* ko = Kimg + (size_t)(b * NT128 + kt) * TILE_HW;
    bf16_t* vo = Vimg + (size_t)(b * NT128 + kt) * TILE_HW;

    // K: chunk u in [z*256, z*256+256): row r = u>>3 (32 rows per quarter), ch = u&7
    {
        const int u = z * 256 + t, r = u >> 3, ch = u & 7;
        const float* p = Kg + src + r * 64 + ch * 8;
        const f32x4 a = *reinterpret_cast<const f32x4*>(p);
        const f32x4 c = *reinterpret_cast<const f32x4*>(p + 4);
        bf16x8 kk;
#pragma unroll
        for (int j = 0; j < 4; ++j) { kk[j] = (bf16_t)a[j]; kk[4 + j] = (bf16_t)c[j]; }
        *reinterpret_cast<bf16x8*>(&ko[r * 64 + ((ch ^ (r & 7)) << 3)]) = kk;
    }

    // V: d = t&63, pc = (t>>6) + z*4  (one bf16x8 output chunk per thread)
    {
        const int d = t & 63, pc = (t >> 6) + z * 4;
        bf16x8 vv;
#pragma unroll
        for (int pw = 0; pw < 8; ++pw) {
            const int pos = pc * 8 + pw;
            const int vkb = ((pos >> 3) & 3) | (((pos >> 2) & 1) << 2) | (((pos >> 5) & 3) << 3);
            const int k   = (vkb << 2) | (pos & 3);
            vv[pw] = (bf16_t)Vg[src + (size_t)k * 64 + d];
        }
        *reinterpret_cast<bf16x8*>(&vo[d * 128 + ((pc ^ (d & 7)) << 3)]) = vv;
    }
}

// ---------------- main kernel (r10 verbatim): 8-wave QB=128 engine, pair K-split ----
// pair p (0..7): tileL = 15-p (nktL = 16-p in 9..16), tileS = p (nktS = p+1 in 1..8)
// role 0 (front): tileL chunks 0..8                      (9 iters) -> partial
// role 1 (back):  tileL chunks 9..nktL-1 + all of tileS  (8 iters) -> partial + direct
__global__ __launch_bounds__(512, 1)
void attn_split_kernel(const float* __restrict__ Qg, float* __restrict__ Og,
                       const bf16_t* __restrict__ Kimg, const bf16_t* __restrict__ Vimg,
                       float* __restrict__ Opart, float* __restrict__ MLb)
{
    const int lin  = blockIdx.x;          // 0..255
    const int xcd  = lin & 7;
    const int b    = xcd * 2 + ((lin >> 3) & 1);   // 2 batches per XCD -> images in L2
    const int p    = (lin >> 4) & 7;
    const int role = lin >> 7;            // both roles of a pair land on the same XCD

    const int nktL = 16 - p;
    const int nktS = p + 1;
    const int cnt1 = role ? (nktL - 9) : 9;   // tileL iters this block
    const int cnt2 = role ? nktS : 0;
    const int total = cnt1 + cnt2;            // 9 (front) / 8 (back)
    const int ktoff = role ? 9 : 0;

    const int tid  = threadIdx.x;
    const int wave = tid >> 6;             // 0..7
    const int lane = tid & 63;
    const int lg   = lane >> 4;
    const int lc   = lane & 15;
    const int lc7  = lc & 7;

    __shared__ __align__(16) bf16_t K_lds[2][TILE_HW];    // 32 KB
    __shared__ __align__(16) bf16_t Vt_lds[2][TILE_HW];   // 32 KB

    const size_t bbase = (size_t)b * L_SEQ * D_H;
    const bf16_t* kimg = Kimg + (size_t)b * NT128 * TILE_HW;
    const bf16_t* vimg = Vimg + (size_t)b * NT128 * TILE_HW;

    auto stage = [&](int kt, int buf) {
        const bf16_t* ks = kimg + (size_t)kt * TILE_HW;
        const bf16_t* vs = vimg + (size_t)kt * TILE_HW;
#pragma unroll
        for (int i = 0; i < 2; ++i) {
            const int c = wave * 2 + i;                    // chunk 0..15 (512 bf16)
            GLD_LDS16(ks + c * 512 + lane * 8, &K_lds[buf][c * 512]);
            GLD_LDS16(vs + c * 512 + lane * 8, &Vt_lds[buf][c * 512]);
        }
    };

    bf16x8 qa[2];
    auto loadQ = [&](int qt_) -> int {
        const int qr = qt_ * QB + wave * 16 + lc;
#pragma unroll
        for (int h = 0; h < 2; ++h) {
            const float* qp = Qg + bbase + (size_t)qr * D_H + h * 32 + lg * 8;
            const f32x4 f0 = *reinterpret_cast<const f32x4*>(qp);
            const f32x4 f1 = *reinterpret_cast<const f32x4*>(qp + 4);
            bf16x8 a;
#pragma unroll
            for (int j = 0; j < 4; ++j) { a[j] = (bf16_t)(f0[j] * QSCALE); a[4 + j] = (bf16_t)(f1[j] * QSCALE); }
            qa[h] = a;
        }
        return qr;
    };

    int qt = 15 - p, nktCur = nktL;
    int qrow = loadQ(qt);

    f32x4 o[4];
#pragma unroll
    for (int dt = 0; dt < 4; ++dt) o[dt] = (f32x4){0.f, 0.f, 0.f, 0.f};
    float m = -1e30f, l = 0.f;   // per-lane l partial in frame m

    auto writePartialL = [&]() {
        float lr = l;
        lr += __shfl_xor(lr, 16);
        lr += __shfl_xor(lr, 32);
        const int slot = (b * 8 + p) * 2 + role;
        float* ob = Opart + (size_t)slot * (QB * D_H);
        const int qL = wave * 16 + lc;   // 0..127
#pragma unroll
        for (int dt = 0; dt < 4; ++dt)
            *reinterpret_cast<f32x4*>(&ob[qL * 64 + dt * 16 + lg * 4]) = o[dt];
        if (lg == 0) { MLb[slot * 256 + qL] = m; MLb[slot * 256 + 128 + qL] = lr; }
    };

    auto seqKt = [&](int j) { return j < cnt1 ? ktoff + j : j - cnt1; };

    stage(seqKt(0), 0);
    __syncthreads();
    int cur = 0;
    for (int j = 0; j < total; ++j) {
        if (role && j == cnt1) {
            // finalize tileL partial (possibly empty), switch to tileS
            writePartialL();
            qt = p; nktCur = nktS; qrow = loadQ(qt);
#pragma unroll
            for (int dt = 0; dt < 4; ++dt) o[dt] = (f32x4){0.f, 0.f, 0.f, 0.f};
            m = -1e30f; l = 0.f;
        }
        const int kt  = seqKt(j);
        const int kb0 = kt * KB;
        if (j + 1 < total) stage(seqKt(j + 1), cur ^ 1);   // prefetch (q-independent)

        // ---- S^T = K Q^T (log2 units): sc[n][r] = S[k=kb0+n*16+lg*4+r][q=qrow] ----
        f32x4 sc[8];
        __builtin_amdgcn_s_setprio(1);
#pragma unroll
        for (int n = 0; n < 8; ++n) {
            f32x4 acc = (f32x4){0.f, 0.f, 0.f, 0.f};
#pragma unroll
            for (int h = 0; h < 2; ++h) {
                const int hw = (n * 16 + lc) * 64 + ((((h << 2) | lg) ^ lc7) << 3);
                const bf16x8 kkb = *reinterpret_cast<const bf16x8*>(&K_lds[cur][hw]);
                acc = __builtin_amdgcn_mfma_f32_16x16x32_bf16(kkb, qa[h], acc, 0, 0, 0);
            }
            sc[n] = acc;
        }
        __builtin_amdgcn_s_setprio(0);
        if (kt == nktCur - 1) {   // diagonal chunk of this tile: causal mask
#pragma unroll
            for (int n = 0; n < 8; ++n)
#pragma unroll
                for (int r = 0; r < 4; ++r)
                    if (kb0 + n * 16 + lg * 4 + r > qrow) sc[n][r] = -1e30f;
        }

        // ---- defer-max online softmax (per-lane; cross-lane only on slow path) ----
        float mxp = fmaxf(fmaxf(sc[0][0], sc[0][1]), fmaxf(sc[0][2], sc[0][3]));
#pragma unroll
        for (int n = 1; n < 8; ++n)
            mxp = fmaxf(mxp, fmaxf(fmaxf(sc[n][0], sc[n][1]), fmaxf(sc[n][2], sc[n][3])));
        if (!__all(mxp <= m + 8.0f)) {
            float mx = mxp;
            mx = fmaxf(mx, __shfl_xor(mx, 16));
            mx = fmaxf(mx, __shfl_xor(mx, 32));
            const float mn = fmaxf(m, mx);
            const float alpha = exp2f(m - mn);
            m = mn;
            l *= alpha;
#pragma unroll
            for (int dt = 0; dt < 4; ++dt)
#pragma unroll
                for (int r = 0; r < 4; ++r) o[dt][r] *= alpha;
        }
        // P packed directly into the PV B-operand layout (phi-permuted V^T image)
        bf16x8 w[4];
        float rs = 0.f;
#pragma unroll
        for (int n = 0; n < 8; ++n) {
            const float p0 = exp2f(sc[n][0] - m), p1 = exp2f(sc[n][1] - m);
            const float p2 = exp2f(sc[n][2] - m), p3 = exp2f(sc[n][3] - m);
            rs += (p0 + p1) + (p2 + p3);
            const int wi = n >> 1, off = (n & 1) * 4;
            w[wi][off + 0] = (bf16_t)p0; w[wi][off + 1] = (bf16_t)p1;
            w[wi][off + 2] = (bf16_t)p2; w[wi][off + 3] = (bf16_t)p3;
        }
        l += rs;

        // ---- O^T += V^T P : P straight from registers, V^T from swizzled LDS ----
        __builtin_amdgcn_s_setprio(1);
#pragma unroll
        for (int ks = 0; ks < 4; ++ks) {
#pragma unroll
            for (int dt = 0; dt < 4; ++dt) {
                const int hw = (dt * 16 + lc) * 128 + ((((ks << 2) | lg) ^ lc7) << 3);
                const bf16x8 vb = *reinterpret_cast<const bf16x8*>(&Vt_lds[cur][hw]);
                o[dt] = __builtin_amdgcn_mfma_f32_16x16x32_bf16(vb, w[ks], o[dt], 0, 0, 0);
            }
        }
        __builtin_amdgcn_s_setprio(0);

        __syncthreads();   // drains vmcnt(0): prefetched stage landed; cur free
        cur ^= 1;
    }

    if (role == 0) {
        writePartialL();                       // front: tileL partial only
    } else {
        // back: tileS is complete -> divide and write directly
        float lr = l;
        lr += __shfl_xor(lr, 16);
        lr += __shfl_xor(lr, 32);
        const float inv = 1.0f / lr;
#pragma unroll
        for (int dt = 0; dt < 4; ++dt) {
            f32x4 val = { o[dt][0] * inv, o[dt][1] * inv, o[dt][2] * inv, o[dt][3] * inv };
            *reinterpret_cast<f32x4*>(Og + bbase + (size_t)qrow * D_H + dt * 16 + lg * 4) = val;
        }
    }
}

// ---------------- merge: 512 blocks x 256 threads (4 blocks per pair) ----------------
__global__ __launch_bounds__(256)
void merge_kernel(const float* __restrict__ Opart, const float* __restrict__ MLb,
                  float* __restrict__ Og)
{
    const int blk     = blockIdx.x;       // 0..511
    const int pairIdx = blk >> 2;         // 0..127  (= b*8 + p)
    const int sub     = blk & 3;
    const int b  = pairIdx >> 3, p = pairIdx & 7;
    const int qt = 15 - p;
    const int t  = threadIdx.x;
    const int q  = sub * 32 + (t >> 3);   // 0..127
    const int dc = (t & 7) * 8;           // 0,8,...,56

    const int slot0 = pairIdx * 2, slot1 = slot0 + 1;
    const float m0 = MLb[slot0 * 256 + q], l0 = MLb[slot0 * 256 + 128 + q];
    const float m1 = MLb[slot1 * 256 + q], l1 = MLb[slot1 * 256 + 128 + q];
    const float mt = fmaxf(m0, m1);
    const float a0 = exp2f(m0 - mt), a1 = exp2f(m1 - mt);
    const float inv = 1.0f / (l0 * a0 + l1 * a1);

    const float* o0 = Opart + (size_t)slot0 * (QB * D_H) + q * 64 + dc;
    const float* o1 = Opart + (size_t)slot1 * (QB * D_H) + q * 64 + dc;
    float* og = Og + (size_t)b * L_SEQ * D_H + (size_t)(qt * QB + q) * D_H + dc;
#pragma unroll
    for (int i = 0; i < 2; ++i) {
        const f32x4 v0 = *reinterpret_cast<const f32x4*>(o0 + i * 4);
        const f32x4 v1 = *reinterpret_cast<const f32x4*>(o1 + i * 4);
        f32x4 r;
#pragma unroll
        for (int k = 0; k < 4; ++k) r[k] = (v0[k] * a0 + v1[k] * a1) * inv;
        *reinterpret_cast<f32x4*>(og + i * 4) = r;
    }
}

// ---------------- fallback (no-ws path, round-6 kernel) ----------------
__global__ __launch_bounds__(256, 2)
void attn_fwd_fb(const float* __restrict__ Qg, const float* __restrict__ Kg,
                 const float* __restrict__ Vg, float* __restrict__ Og)
{
    const int lin  = blockIdx.x;
    const int xcd  = lin & 7;
    const int slot = lin >> 3;
    const int half = slot >> 5;
    const int qi   = slot & 31;
    const int b    = xcd * 2 + half;
    const int qt   = half ? qi : (31 - qi);

    const int tid  = threadIdx.x;
    const int lane = tid & 63;
    const int lg   = lane >> 4;
    const int lc   = lane & 15;
    const int lc7  = lc & 7;

    __shared__ __align__(16) bf16_t K_lds[2][KB * D_H];
    __shared__ __align__(16) bf16_t Vt_lds[2][D_H * KB];

    const size_t bbase = (size_t)b * L_SEQ * D_H;
    const int qrow = qt * 64 + (tid >> 6) * 16 + lc;
    bf16x8 qa[2];
#pragma unroll
    for (int h = 0; h < 2; ++h) {
        const float* qp = Qg + bbase + (size_t)qrow * D_H + h * 32 + lg * 8;
        const f32x4 f0 = *reinterpret_cast<const f32x4*>(qp);
        const f32x4 f1 = *reinterpret_cast<const f32x4*>(qp + 4);
        bf16x8 a;
#pragma unroll
        for (int j = 0; j < 4; ++j) { a[j] = (bf16_t)(f0[j] * QSCALE); a[4 + j] = (bf16_t)(f1[j] * QSCALE); }
        qa[h] = a;
    }
    f32x4 o[4];
#pragma unroll
    for (int dt = 0; dt < 4; ++dt) o[dt] = (f32x4){0.f, 0.f, 0.f, 0.f};
    float m = -1e30f, l = 0.f;
    const int nkt = (qt + 2) >> 1;
    const int vkb  = tid & 31;
    const int vdg  = tid >> 5;
    const int vpos = ((vkb >> 3) << 5) + ((vkb & 3) << 3) + (((vkb >> 2) & 1) << 2);
    f32x4 kreg[8], vreg[8];

    auto issueK = [&](int kt) {
        const int kbase = kt * KB;
#pragma unroll
        for (int i = 0; i < 4; ++i) {
            const int u = i * 256 + tid;
            const int r = u >> 3, ch = u & 7;
            const float* p = Kg + bbase + (size_t)(kbase + r) * D_H + ch * 8;
            kreg[2 * i]     = *reinterpret_cast<const f32x4*>(p);
            kreg[2 * i + 1] = *reinterpret_cast<const f32x4*>(p + 4);
        }
    };
    auto issueV = [&](int kt) {
        const int kbase = kt * KB;
#pragma unroll
        for (int d2 = 0; d2 < 2; ++d2)
#pragma unroll
            for (int i = 0; i < 4; ++i)
                vreg[d2 * 4 + i] = *reinterpret_cast<const f32x4*>(
                    Vg + bbase + (size_t)(kbase + vkb * 4 + i) * D_H + (vdg + d2 * 8) * 4);
    };
    auto writeK = [&](int buf) {
#pragma unroll
        for (int i = 0; i < 4; ++i) {
            const int u = i * 256 + tid;
            const int r = u >> 3, ch = u & 7;
            bf16x8 kk;
#pragma unroll
            for (int j = 0; j < 4; ++j) { kk[j] = (bf16_t)kreg[2 * i][j]; kk[4 + j] = (bf16_t)kreg[2 * i + 1][j]; }
            *reinterpret_cast<bf16x8*>(&K_lds[buf][r * 64 + ((ch ^ (r & 7)) << 3)]) = kk;
        }
    };
    auto writeV = [&](int buf) {
#pragma unroll
        for (int d2 = 0; d2 < 2; ++d2) {
            const int db = vdg + d2 * 8;
#pragma unroll
            for (int j = 0; j < 4; ++j) {
                const int d = db * 4 + j;
                bf16x4 cj = { (bf16_t)vreg[d2 * 4 + 0][j], (bf16_t)vreg[d2 * 4 + 1][j],
                              (bf16_t)vreg[d2 * 4 + 2][j], (bf16_t)vreg[d2 * 4 + 3][j] };
                const int hw = d * 128 + (((vpos >> 3) ^ (d & 7)) << 3) + (vpos & 7);
                *reinterpret_cast<bf16x4*>(&Vt_lds[buf][hw]) = cj;
            }
        }
    };

    issueK(0); issueV(0); writeK(0); writeV(0);
    __syncthreads();
    int cur = 0;
    for (int kt = 0; kt < nkt; ++kt) {
        const bool last = (kt == nkt - 1);
        const int kbase = kt * KB;
        if (!last) issueK(kt + 1);
        f32x4 sc[8];
#pragma unroll
        for (int n = 0; n < 8; ++n) {
            f32x4 acc = (f32x4){0.f, 0.f, 0.f, 0.f};
#pragma unroll
            for (int h = 0; h < 2; ++h) {
                const int hw = (n * 16 + lc) * 64 + ((((h << 2) | lg) ^ lc7) << 3);
                const bf16x8 kkb = *reinterpret_cast<const bf16x8*>(&K_lds[cur][hw]);
                acc = __builtin_amdgcn_mfma_f32_16x16x32_bf16(kkb, qa[h], acc, 0, 0, 0);
            }
            sc[n] = acc;
        }
        if (!last) issueV(kt + 1);
        if (last) {
#pragma unroll
            for (int n = 0; n < 8; ++n)
#pragma unroll
                for (int r = 0; r < 4; ++r)
                    if (kbase + n * 16 + lg * 4 + r > qrow) sc[n][r] = -1e30f;
        }
        float mxp = fmaxf(fmaxf(sc[0][0], sc[0][1]), fmaxf(sc[0][2], sc[0][3]));
#pragma unroll
        for (int n = 1; n < 8; ++n)
            mxp = fmaxf(mxp, fmaxf(fmaxf(sc[n][0], sc[n][1]), fmaxf(sc[n][2], sc[n][3])));
        if (!__all(mxp <= m + 8.0f)) {
            float mx = mxp;
            mx = fmaxf(mx, __shfl_xor(mx, 16));
            mx = fmaxf(mx, __shfl_xor(mx, 32));
            const float mn = fmaxf(m, mx);
            const float alpha = exp2f(m - mn);
            m = mn; l *= alpha;
#pragma unroll
            for (int dt = 0; dt < 4; ++dt)
#pragma unroll
                for (int r = 0; r < 4; ++r) o[dt][r] *= alpha;
        }
        bf16x8 w[4];
        float rs = 0.f;
#pragma unroll
        for (int n = 0; n < 8; ++n) {
            const float p0 = exp2f(sc[n][0] - m), p1 = exp2f(sc[n][1] - m);
            const float p2 = exp2f(sc[n][2] - m), p3 = exp2f(sc[n][3] - m);
            rs += (p0 + p1) + (p2 + p3);
            const int wi = n >> 1, off = (n & 1) * 4;
            w[wi][off + 0] = (bf16_t)p0; w[wi][off + 1] = (bf16_t)p1;
            w[wi][off + 2] = (bf16_t)p2; w[wi][off + 3] = (bf16_t)p3;
        }
        l += rs;
        if (!last) writeK(cur ^ 1);
#pragma unroll
        for (int ks = 0; ks < 4; ++ks) {
#pragma unroll
            for (int dt = 0; dt < 4; ++dt) {
                const int hw = (dt * 16 + lc) * 128 + ((((ks << 2) | lg) ^ lc7) << 3);
                const bf16x8 vb = *reinterpret_cast<const bf16x8*>(&Vt_lds[cur][hw]);
                o[dt] = __builtin_amdgcn_mfma_f32_16x16x32_bf16(vb, w[ks], o[dt], 0, 0, 0);
            }
        }
        if (!last) writeV(cur ^ 1);
        __syncthreads();
        cur ^= 1;
    }
    float lr = l;
    lr += __shfl_xor(lr, 16);
    lr += __shfl_xor(lr, 32);
    const float inv = 1.0f / lr;
#pragma unroll
    for (int dt = 0; dt < 4; ++dt) {
        f32x4 val = { o[dt][0] * inv, o[dt][1] * inv, o[dt][2] * inv, o[dt][3] * inv };
        *reinterpret_cast<f32x4*>(Og + bbase + (size_t)qrow * D_H + dt * 16 + lg * 4) = val;
    }
}

extern "C" void kernel_launch(void* const* d_in, const int* in_sizes, int n_in,
                              void* d_out, int out_size, void* d_ws, size_t ws_size,
                              hipStream_t stream)
{
    const float* Q = (const float*)d_in[0];
    const float* K = (const float*)d_in[1];
    const float* V = (const float*)d_in[2];
    float* O = (float*)d_out;

    const size_t img_bytes = 2 * IMG_ELEMS * sizeof(bf16_t);              // 8 MB
    const size_t opart_fl  = (size_t)B_SZ * 8 * 2 * (QB * D_H);           // 2M floats
    const size_t ml_fl     = (size_t)B_SZ * 8 * 2 * 256;                  // 64K floats
    const size_t need = img_bytes + (opart_fl + ml_fl) * sizeof(float);   // ~16.9 MB

    if (ws_size >= need) {
        bf16_t* Kimg  = (bf16_t*)d_ws;
        bf16_t* Vimg  = Kimg + IMG_ELEMS;
        float*  Opart = (float*)((char*)d_ws + img_bytes);
        float*  MLb   = Opart + opart_fl;
        preproc_kernel<<<dim3(NT128, B_SZ, 4), dim3(256), 0, stream>>>(K, V, Kimg, Vimg);
        attn_split_kernel<<<dim3(256), dim3(512), 0, stream>>>(Q, O, Kimg, Vimg, Opart, MLb);
        merge_kernel<<<dim3(512), dim3(256), 0, stream>>>(Opart, MLb, O);
    } else {
        attn_fwd_fb<<<dim3(512), dim3(256), 0, stream>>>(Q, K, V, O);
    }
}